// Round 11
// baseline (743.757 us; speedup 1.0000x reference)
//
#include <hip/hip_runtime.h>
#include <stdint.h>

#define Hh 8
#define Bb 32
#define Tt 512
#define Ee 512
#define Nn 16384            // Bb*Tt
#define GAMMA_ 1.5f
#define BN_EPS_ 1e-5f

typedef _Float16 f16x4 __attribute__((ext_vector_type(4)));
typedef _Float16 f16x8 __attribute__((ext_vector_type(8)));
typedef float    f32x4 __attribute__((ext_vector_type(4)));

__device__ __forceinline__ void async_ld16(void* lds, const void* g) {
    __builtin_amdgcn_global_load_lds(
        (const __attribute__((address_space(1))) void*)g,
        (__attribute__((address_space(3))) void*)lds, 16, 0, 0);
}

// Full-wave (64-lane) f32 sum via DPP (pure VALU, no DS pipe).
__device__ __forceinline__ float dpp_sum64(float v) {
    int t;
    t = __builtin_amdgcn_update_dpp(0, __float_as_int(v), 0x111, 0xf, 0xf, true);
    v += __int_as_float(t);
    t = __builtin_amdgcn_update_dpp(0, __float_as_int(v), 0x112, 0xf, 0xf, true);
    v += __int_as_float(t);
    t = __builtin_amdgcn_update_dpp(0, __float_as_int(v), 0x114, 0xf, 0xf, true);
    v += __int_as_float(t);
    t = __builtin_amdgcn_update_dpp(0, __float_as_int(v), 0x118, 0xf, 0xf, true);
    v += __int_as_float(t);
    t = __builtin_amdgcn_update_dpp(0, __float_as_int(v), 0x142, 0xf, 0xf, true);
    v += __int_as_float(t);
    t = __builtin_amdgcn_update_dpp(0, __float_as_int(v), 0x143, 0xf, 0xf, true);
    v += __int_as_float(t);
    return __int_as_float(__builtin_amdgcn_readlane(__float_as_int(v), 63));
}

// Full-wave f32 max via DPP. old=src + bound_ctrl=false => invalid lanes are
// identity under fmax (no 0.0 injection; safe for all-negative inputs).
__device__ __forceinline__ float dpp_max64(float v) {
    int t;
    t = __builtin_amdgcn_update_dpp(__float_as_int(v), __float_as_int(v), 0x111, 0xf, 0xf, false);
    v = fmaxf(v, __int_as_float(t));
    t = __builtin_amdgcn_update_dpp(__float_as_int(v), __float_as_int(v), 0x112, 0xf, 0xf, false);
    v = fmaxf(v, __int_as_float(t));
    t = __builtin_amdgcn_update_dpp(__float_as_int(v), __float_as_int(v), 0x114, 0xf, 0xf, false);
    v = fmaxf(v, __int_as_float(t));
    t = __builtin_amdgcn_update_dpp(__float_as_int(v), __float_as_int(v), 0x118, 0xf, 0xf, false);
    v = fmaxf(v, __int_as_float(t));
    t = __builtin_amdgcn_update_dpp(__float_as_int(v), __float_as_int(v), 0x142, 0xf, 0xf, false);
    v = fmaxf(v, __int_as_float(t));
    t = __builtin_amdgcn_update_dpp(__float_as_int(v), __float_as_int(v), 0x143, 0xf, 0xf, false);
    v = fmaxf(v, __int_as_float(t));
    return __int_as_float(__builtin_amdgcn_readlane(__float_as_int(v), 63));
}

// ---------------- K0: fp32 -> f16 convert (x then W) + zero BN accumulators -----
__global__ __launch_bounds__(256) void cvt_kernel(const float* __restrict__ x,
                                                  const float* __restrict__ W,
                                                  _Float16* __restrict__ xh,
                                                  _Float16* __restrict__ wh,
                                                  float* __restrict__ sums) {
    const int NX = Bb * Tt * Ee;               // 8388608, divisible by 4
    const int tid_g = blockIdx.x * 256 + threadIdx.x;   // 0..2621439
    int i = tid_g * 4;
    if (i < NX) {
        float4 v = *(const float4*)(x + i);
        f16x4 o = {(_Float16)v.x, (_Float16)v.y, (_Float16)v.z, (_Float16)v.w};
        *(f16x4*)(xh + i) = o;
    } else {
        int j = i - NX;                        // 0 .. 2097151
        float4 v = *(const float4*)(W + j);
        f16x4 o = {(_Float16)v.x, (_Float16)v.y, (_Float16)v.z, (_Float16)v.w};
        *(f16x4*)(wh + j) = o;
    }
    int zi = tid_g - (2621440 - 2048);         // last 2048 threads
    if (zi >= 0) {
        float4 zz = {0.f, 0.f, 0.f, 0.f};
        ((float4*)sums)[zi] = zz;              // sums+sumsq contiguous, 32 KB
    }
}

// ---------------- K1: batched NT GEMM, 256x256, BK=64, 8-phase counted-vmcnt ----
// R8-verified schedule; measured 91.4 us via R9 double-launch (near structural
// floor; schedule variants R3-R8 all null -- consistent with mixed-traffic
// limit, not schedule limit).
__global__ __launch_bounds__(512, 2) void gemm_kernel(const _Float16* __restrict__ A,
                                                      const _Float16* __restrict__ Bm,
                                                      _Float16* __restrict__ C,
                                                      float* __restrict__ sums,
                                                      float* __restrict__ sumsq) {
    __shared__ alignas(16) _Float16 As[2][256 * 64];   // 2 x 32 KB
    __shared__ alignas(16) _Float16 Bs[2][256 * 64];   // 2 x 32 KB
    // XCD-aware swizzle: 1024 blocks, 8 XCDs, 128 blocks (one head) per XCD.
    const int id  = (blockIdx.x & 7) * 128 + (blockIdx.x >> 3);
    const int h   = id >> 7;
    const int rem = id & 127;
    const int mb  = (rem >> 1) * 256;          // 64 row-blocks
    const int nb  = (rem & 1) * 256;           // 2 col-blocks

    const int t    = threadIdx.x;              // 0..511
    const int lane = t & 63;
    const int w    = t >> 6;                   // 0..7
    const int wrow = (w >> 2) * 128;           // 0,128
    const int wcol = (w & 3) * 64;             // 0,64,128,192
    const int quad = lane >> 4;
    const int l16  = lane & 15;

    // staging: thread t covers row (t>>3)+q*64, chunk slot t&7; global k-chunk
    // c = (slot - (row>>1)) & 7 (R4-verified). LDS index = q*4096 + t*8.
    const int c = ((t & 7) - ((t >> 4) & 7)) & 7;
    const _Float16* Ap = A + (size_t)(mb + (t >> 3)) * Ee + c * 8;
    const _Float16* Bp = Bm + (size_t)h * Ee * Ee + (size_t)(nb + (t >> 3)) * Ee + c * 8;

#define STG_A(b, q, tt) async_ld16(&As[b][(q) * 4096 + t * 8], Ap + (tt) * 64 + (q) * 64 * Ee)
#define STG_B(b, q, tt) async_ld16(&Bs[b][(q) * 4096 + t * 8], Bp + (tt) * 64 + (q) * 64 * Ee)
#define BAR() do { asm volatile("" ::: "memory"); __builtin_amdgcn_s_barrier(); \
                   asm volatile("" ::: "memory"); } while (0)

    f32x4 acc[8][4] = {};
    f16x8 a8[4], b8[2][4];

    auto rdA = [&](int bsel, int mt, int kk) {
        int row = wrow + mt * 16 + l16;
        int sl  = ((kk * 4 + quad) + ((row >> 1) & 7)) & 7;
        return *(const f16x8*)(&As[bsel][row * 64 + sl * 8]);
    };
    auto rdB = [&](int bsel, int nt, int kk) {
        int row = wcol + nt * 16 + l16;
        int sl  = ((kk * 4 + quad) + ((row >> 1) & 7)) & 7;
        return *(const f16x8*)(&Bs[bsel][row * 64 + sl * 8]);
    };
    auto mm = [&](int mh, int kk) {
        __builtin_amdgcn_s_setprio(1);
#pragma unroll
        for (int j = 0; j < 4; ++j)
#pragma unroll
            for (int nt = 0; nt < 4; ++nt)
                acc[mh * 4 + j][nt] = __builtin_amdgcn_mfma_f32_16x16x32_f16(
                    a8[j], b8[kk][nt], acc[mh * 4 + j][nt], 0, 0, 0);
        __builtin_amdgcn_s_setprio(0);
    };

    // prologue: tile0 full (8 loads) + tile1 partial A q0,q2 + B q0-3 (6 loads)
#pragma unroll
    for (int q = 0; q < 4; ++q) { STG_A(0, q, 0); STG_B(0, q, 0); }
    STG_A(1, 0, 1); STG_A(1, 2, 1);
    STG_B(1, 0, 1); STG_B(1, 1, 1); STG_B(1, 2, 1); STG_B(1, 3, 1);
    asm volatile("s_waitcnt vmcnt(6)" ::: "memory");   // retire tile0's 8
    BAR();

#pragma unroll 1
    for (int i = 0; i < 4; ++i) {
        const int T1 = 2 * i + 1;
        const int T2 = 2 * i + 2;              // next even tile -> buf0
        const int T3 = 2 * i + 3;              // next odd tile  -> buf1
        const bool st = (i < 3);

        // ph0: buf0 kk0 mt0-3 (A q0,q2) + B kk0; stage T1 A q1,q3 -> buf1
#pragma unroll
        for (int nt = 0; nt < 4; ++nt) b8[0][nt] = rdB(0, nt, 0);
#pragma unroll
        for (int j = 0; j < 4; ++j) a8[j] = rdA(0, j, 0);
        STG_A(1, 1, T1); STG_A(1, 3, T1);
        BAR();
        mm(0, 0);
        BAR();

        // ph1: buf0 kk1 mt0-3 + B kk1
#pragma unroll
        for (int nt = 0; nt < 4; ++nt) b8[1][nt] = rdB(0, nt, 1);
#pragma unroll
        for (int j = 0; j < 4; ++j) a8[j] = rdA(0, j, 1);
        BAR();
        mm(0, 1);
        BAR();

        // ph2: buf0 kk0 mt4-7 (A q1,q3; B from regs); stage T2 A q0,q2 + B q0,q1
#pragma unroll
        for (int j = 0; j < 4; ++j) a8[j] = rdA(0, 4 + j, 0);
        if (st) { STG_A(0, 0, T2); STG_A(0, 2, T2); STG_B(0, 0, T2); STG_B(0, 1, T2); }
        BAR();
        mm(1, 0);
        BAR();

        // ph3: buf0 kk1 mt4-7; stage T2 B q2,q3; K-tile boundary wait
#pragma unroll
        for (int j = 0; j < 4; ++j) a8[j] = rdA(0, 4 + j, 1);
        if (st) { STG_B(0, 2, T2); STG_B(0, 3, T2); }
        BAR();
        mm(1, 1);
        if (st) asm volatile("s_waitcnt vmcnt(6)" ::: "memory");  // retire T1's 8
        else    asm volatile("s_waitcnt vmcnt(0)" ::: "memory");  // last tile
        BAR();

        // ph4: buf1 kk0 mt0-3 + B kk0; stage T2 A q1,q3 -> buf0
#pragma unroll
        for (int nt = 0; nt < 4; ++nt) b8[0][nt] = rdB(1, nt, 0);
#pragma unroll
        for (int j = 0; j < 4; ++j) a8[j] = rdA(1, j, 0);
        if (st) { STG_A(0, 1, T2); STG_A(0, 3, T2); }
        BAR();
        mm(0, 0);
        BAR();

        // ph5: buf1 kk1 mt0-3 + B kk1
#pragma unroll
        for (int nt = 0; nt < 4; ++nt) b8[1][nt] = rdB(1, nt, 1);
#pragma unroll
        for (int j = 0; j < 4; ++j) a8[j] = rdA(1, j, 1);
        BAR();
        mm(0, 1);
        BAR();

        // ph6: buf1 kk0 mt4-7; stage T3 A q0,q2 + B q0,q1 -> buf1
#pragma unroll
        for (int j = 0; j < 4; ++j) a8[j] = rdA(1, 4 + j, 0);
        if (st) { STG_A(1, 0, T3); STG_A(1, 2, T3); STG_B(1, 0, T3); STG_B(1, 1, T3); }
        BAR();
        mm(1, 0);
        BAR();

        // ph7: buf1 kk1 mt4-7; stage T3 B q2,q3; K-tile boundary wait
#pragma unroll
        for (int j = 0; j < 4; ++j) a8[j] = rdA(1, 4 + j, 1);
        if (st) { STG_B(1, 2, T3); STG_B(1, 3, T3); }
        BAR();
        mm(1, 1);
        if (st) {
            asm volatile("s_waitcnt vmcnt(6)" ::: "memory");      // retire T2's 8
            BAR();
        }
    }
#undef STG_A
#undef STG_B
#undef BAR

    // BN partial sums: reduce over rows (mt,r) then across quads (lanes xor 16,32)
#pragma unroll
    for (int nt = 0; nt < 4; ++nt) {
        float sv = 0.f, ss = 0.f;
#pragma unroll
        for (int mt = 0; mt < 8; ++mt)
#pragma unroll
            for (int rr = 0; rr < 4; ++rr) { float v = acc[mt][nt][rr]; sv += v; ss += v * v; }
        sv += __shfl_xor(sv, 16, 64); sv += __shfl_xor(sv, 32, 64);
        ss += __shfl_xor(ss, 16, 64); ss += __shfl_xor(ss, 32, 64);
        if (quad == 0) {
            int col = nb + wcol + nt * 16 + l16;
            atomicAdd(&sums[h * Ee + col], sv);
            atomicAdd(&sumsq[h * Ee + col], ss);
        }
    }

    // store C (f16): C/D layout col=lane&15, row=quad*4+reg
    _Float16* Cp = C + (size_t)h * Nn * Ee;
#pragma unroll
    for (int mt = 0; mt < 8; ++mt)
#pragma unroll
        for (int rr = 0; rr < 4; ++rr) {
            int row = mb + wrow + mt * 16 + quad * 4 + rr;
            size_t off = (size_t)row * Ee + nb + wcol + l16;
#pragma unroll
            for (int nt = 0; nt < 4; ++nt)
                Cp[off + nt * 16] = (_Float16)acc[mt][nt][rr];
        }
}

// ---------------- K2: finalize BN stats into affine coefs -----------------------
__global__ __launch_bounds__(256) void stats_kernel(const float* __restrict__ sums,
                                                    const float* __restrict__ sumsq,
                                                    const float* __restrict__ bnw,
                                                    const float* __restrict__ bnb,
                                                    float* __restrict__ cA,
                                                    float* __restrict__ cB) {
    int i = blockIdx.x * 256 + threadIdx.x;    // 0..4095
    float mean = sums[i] * (1.0f / Nn);
    float var  = sumsq[i] * (1.0f / Nn) - mean * mean;
    float inv  = rsqrtf(var + BN_EPS_);
    float a    = bnw[i] * inv;
    cA[i] = a;
    cB[i] = bnb[i] - mean * a;
}

// ---------------- K3: per-row head scan: sparsemax (Michelot, max-seeded) -------
// R8-proven 1-row-per-wave version (R10's 2-row variant was +5 us). THIS
// ROUND: launched TWICE for attribution (pure function of x/lg/cA/cB ->
// idempotent; run 2 lands last). dur_us - 645 = rows' true duration.
__global__ __launch_bounds__(256) void rows_kernel(const float* __restrict__ x,
                                                   const _Float16* __restrict__ lg,
                                                   const float* __restrict__ cA,
                                                   const float* __restrict__ cB,
                                                   float* __restrict__ out) {
    const int n    = blockIdx.x * 4 + (threadIdx.x >> 6);
    const int lane = threadIdx.x & 63;
    const int e0   = lane * 4;                 // first chunk; second at +256
    const int bb   = n >> 9;                   // n / Tt
    const int tt   = n & 511;                  // n % Tt

    float xr[8], prior[8];
    {
        const float* xp = x + (size_t)n * Ee;
        float4 x0 = *(const float4*)(xp + e0);
        float4 x1 = *(const float4*)(xp + 256 + e0);
        xr[0]=x0.x; xr[1]=x0.y; xr[2]=x0.z; xr[3]=x0.w;
        xr[4]=x1.x; xr[5]=x1.y; xr[6]=x1.z; xr[7]=x1.w;
    }
#pragma unroll
    for (int j = 0; j < 8; ++j) prior[j] = 1.0f;

    float* omx = out;                               // (H,B,T,E) flat = (H,N,E)
    float* omk = out + (size_t)Hh * Nn * Ee;        // (B,H,T,E)

    const _Float16* lrow = lg + (size_t)n * Ee;
    f16x4 l0 = *(const f16x4*)(lrow + e0);
    f16x4 l1 = *(const f16x4*)(lrow + 256 + e0);

#pragma unroll 1
    for (int h = 0; h < Hh; ++h) {
        // depth-1 prefetch of next head's logits (independent of prior chain)
        f16x4 p0 = l0, p1 = l1;
        if (h + 1 < Hh) {
            const _Float16* lnx = lrow + (size_t)(h + 1) * Nn * Ee;
            p0 = *(const f16x4*)(lnx + e0);
            p1 = *(const f16x4*)(lnx + 256 + e0);
        }
        float z[8];
        {
            const float* ap = cA + h * Ee + e0;
            const float* bp = cB + h * Ee + e0;
            float4 a0 = *(const float4*)(ap);
            float4 b0 = *(const float4*)(bp);
            float4 a1 = *(const float4*)(ap + 256);
            float4 b1 = *(const float4*)(bp + 256);
            z[0] = ((float)l0[0] * a0.x + b0.x) * prior[0];
            z[1] = ((float)l0[1] * a0.y + b0.y) * prior[1];
            z[2] = ((float)l0[2] * a0.z + b0.z) * prior[2];
            z[3] = ((float)l0[3] * a0.w + b0.w) * prior[3];
            z[4] = ((float)l1[0] * a1.x + b1.x) * prior[4];
            z[5] = ((float)l1[1] * a1.y + b1.y) * prior[5];
            z[6] = ((float)l1[2] * a1.z + b1.z) * prior[6];
            z[7] = ((float)l1[3] * a1.w + b1.w) * prior[7];
        }

        // Michelot seeded at tau0 = max - 1 (exact sparsemax threshold).
        float mx = z[0];
#pragma unroll
        for (int j = 1; j < 8; ++j) mx = fmaxf(mx, z[j]);
        float tau = dpp_max64(mx) - 1.0f;
        int cprev = -1;
#pragma unroll 1
        for (int it = 0; it < 64; ++it) {
            float s2 = 0.f;
            int cnt = 0;
#pragma unroll
            for (int j = 0; j < 8; ++j) {
                bool p = z[j] > tau;
                s2 += p ? z[j] : 0.0f;
                cnt += (int)__popcll(__ballot(p));
            }
            float S = dpp_sum64(s2);
            if (cnt == cprev) break;
            cprev = cnt;
            tau = (S - 1.0f) / (float)cnt;
        }

        size_t oxoff = ((size_t)h * Nn + n) * Ee + e0;
        size_t okoff = (((size_t)bb * Hh + h) * Tt + tt) * Ee + e0;
        f32x4 vx, vm;
#pragma unroll
        for (int j = 0; j < 4; ++j) {
            float m = fmaxf(z[j] - tau, 0.0f);
            prior[j] *= fmaxf(GAMMA_ - m, 0.0f);
            vm[j] = m; vx[j] = xr[j] * m;
        }
        __builtin_nontemporal_store(vx, (f32x4*)(omx + oxoff));
        __builtin_nontemporal_store(vm, (f32x4*)(omk + okoff));
#pragma unroll
        for (int j = 0; j < 4; ++j) {
            float m = fmaxf(z[4 + j] - tau, 0.0f);
            prior[4 + j] *= fmaxf(GAMMA_ - m, 0.0f);
            vm[j] = m; vx[j] = xr[4 + j] * m;
        }
        __builtin_nontemporal_store(vx, (f32x4*)(omx + oxoff + 256));
        __builtin_nontemporal_store(vm, (f32x4*)(omk + okoff + 256));
        l0 = p0; l1 = p1;
    }
}

extern "C" void kernel_launch(void* const* d_in, const int* in_sizes, int n_in,
                              void* d_out, int out_size, void* d_ws, size_t ws_size,
                              hipStream_t stream) {
    const float* x   = (const float*)d_in[0];
    const float* W   = (const float*)d_in[1];
    const float* bnw = (const float*)d_in[2];
    const float* bnb = (const float*)d_in[3];
    float* out = (float*)d_out;

    uint8_t* ws = (uint8_t*)d_ws;
    _Float16* xh = (_Float16*)(ws);                    // 16,777,216 B
    _Float16* wh = (_Float16*)(ws + 16777216);         //  4,194,304 B
    _Float16* lg = (_Float16*)(ws + 20971520);         // 134,217,728 B
    float* sums  = (float*)(ws + 155189248);           // 16,384 B
    float* sumsq = (float*)(ws + 155205632);           // 16,384 B
    float* cA    = (float*)(ws + 155222016);           // 16,384 B
    float* cB    = (float*)(ws + 155238400);           // 16,384 B (total ~148 MB)

    cvt_kernel<<<10240, 256, 0, stream>>>(x, W, xh, wh, sums);   // also zeros sums+sumsq
    gemm_kernel<<<1024, 512, 0, stream>>>(xh, wh, lg, sums, sumsq);
    stats_kernel<<<16, 256, 0, stream>>>(sums, sumsq, bnw, bnb, cA, cB);

    // ATTRIBUTION EXPERIMENT (this round): rows launched twice. Pure function
    // of (x, lg, cA, cB) -> identical outputs; run 2 lands last. dur_us - 645
    // = rows' true duration.
    rows_kernel<<<4096, 256, 0, stream>>>(x, lg, cA, cB, out);
    rows_kernel<<<4096, 256, 0, stream>>>(x, lg, cA, cB, out);
}

// Round 12
// 645.403 us; speedup vs baseline: 1.1524x; 1.1524x over previous
//
#include <hip/hip_runtime.h>
#include <stdint.h>

#define Hh 8
#define Bb 32
#define Tt 512
#define Ee 512
#define Nn 16384            // Bb*Tt
#define GAMMA_ 1.5f
#define BN_EPS_ 1e-5f

typedef _Float16 f16x4 __attribute__((ext_vector_type(4)));
typedef _Float16 f16x8 __attribute__((ext_vector_type(8)));
typedef float    f32x4 __attribute__((ext_vector_type(4)));

__device__ __forceinline__ void async_ld16(void* lds, const void* g) {
    __builtin_amdgcn_global_load_lds(
        (const __attribute__((address_space(1))) void*)g,
        (__attribute__((address_space(3))) void*)lds, 16, 0, 0);
}

// Full-wave (64-lane) f32 sum via DPP (pure VALU, no DS pipe).
__device__ __forceinline__ float dpp_sum64(float v) {
    int t;
    t = __builtin_amdgcn_update_dpp(0, __float_as_int(v), 0x111, 0xf, 0xf, true);
    v += __int_as_float(t);
    t = __builtin_amdgcn_update_dpp(0, __float_as_int(v), 0x112, 0xf, 0xf, true);
    v += __int_as_float(t);
    t = __builtin_amdgcn_update_dpp(0, __float_as_int(v), 0x114, 0xf, 0xf, true);
    v += __int_as_float(t);
    t = __builtin_amdgcn_update_dpp(0, __float_as_int(v), 0x118, 0xf, 0xf, true);
    v += __int_as_float(t);
    t = __builtin_amdgcn_update_dpp(0, __float_as_int(v), 0x142, 0xf, 0xf, true);
    v += __int_as_float(t);
    t = __builtin_amdgcn_update_dpp(0, __float_as_int(v), 0x143, 0xf, 0xf, true);
    v += __int_as_float(t);
    return __int_as_float(__builtin_amdgcn_readlane(__float_as_int(v), 63));
}

// Full-wave f32 max via DPP. old=src + bound_ctrl=false => invalid lanes are
// identity under fmax (no 0.0 injection; safe for all-negative inputs).
__device__ __forceinline__ float dpp_max64(float v) {
    int t;
    t = __builtin_amdgcn_update_dpp(__float_as_int(v), __float_as_int(v), 0x111, 0xf, 0xf, false);
    v = fmaxf(v, __int_as_float(t));
    t = __builtin_amdgcn_update_dpp(__float_as_int(v), __float_as_int(v), 0x112, 0xf, 0xf, false);
    v = fmaxf(v, __int_as_float(t));
    t = __builtin_amdgcn_update_dpp(__float_as_int(v), __float_as_int(v), 0x114, 0xf, 0xf, false);
    v = fmaxf(v, __int_as_float(t));
    t = __builtin_amdgcn_update_dpp(__float_as_int(v), __float_as_int(v), 0x118, 0xf, 0xf, false);
    v = fmaxf(v, __int_as_float(t));
    t = __builtin_amdgcn_update_dpp(__float_as_int(v), __float_as_int(v), 0x142, 0xf, 0xf, false);
    v = fmaxf(v, __int_as_float(t));
    t = __builtin_amdgcn_update_dpp(__float_as_int(v), __float_as_int(v), 0x143, 0xf, 0xf, false);
    v = fmaxf(v, __int_as_float(t));
    return __int_as_float(__builtin_amdgcn_readlane(__float_as_int(v), 63));
}

// ---------------- K0: fp32 -> f16 convert (x then W) + zero BN accumulators -----
__global__ __launch_bounds__(256) void cvt_kernel(const float* __restrict__ x,
                                                  const float* __restrict__ W,
                                                  _Float16* __restrict__ xh,
                                                  _Float16* __restrict__ wh,
                                                  float* __restrict__ sums) {
    const int NX = Bb * Tt * Ee;               // 8388608, divisible by 4
    const int tid_g = blockIdx.x * 256 + threadIdx.x;   // 0..2621439
    int i = tid_g * 4;
    if (i < NX) {
        float4 v = *(const float4*)(x + i);
        f16x4 o = {(_Float16)v.x, (_Float16)v.y, (_Float16)v.z, (_Float16)v.w};
        *(f16x4*)(xh + i) = o;
    } else {
        int j = i - NX;                        // 0 .. 2097151
        float4 v = *(const float4*)(W + j);
        f16x4 o = {(_Float16)v.x, (_Float16)v.y, (_Float16)v.z, (_Float16)v.w};
        *(f16x4*)(wh + j) = o;
    }
    int zi = tid_g - (2621440 - 2048);         // last 2048 threads
    if (zi >= 0) {
        float4 zz = {0.f, 0.f, 0.f, 0.f};
        ((float4*)sums)[zi] = zz;              // sums+sumsq contiguous, 32 KB
    }
}

// ---------------- K1: batched NT GEMM, 256x256, BK=64, 8-phase counted-vmcnt ----
// R8-verified schedule; measured 91.4 us via R9 double-launch. Near structural
// floor: six schedule variants (2-phase dbuf, coarse 4-buf, BK=64+T1+T5,
// 3-buf counted-vmcnt, 8-phase T3+T4+T5) all within noise or worse.
__global__ __launch_bounds__(512, 2) void gemm_kernel(const _Float16* __restrict__ A,
                                                      const _Float16* __restrict__ Bm,
                                                      _Float16* __restrict__ C,
                                                      float* __restrict__ sums,
                                                      float* __restrict__ sumsq) {
    __shared__ alignas(16) _Float16 As[2][256 * 64];   // 2 x 32 KB
    __shared__ alignas(16) _Float16 Bs[2][256 * 64];   // 2 x 32 KB
    // XCD-aware swizzle: 1024 blocks, 8 XCDs, 128 blocks (one head) per XCD.
    const int id  = (blockIdx.x & 7) * 128 + (blockIdx.x >> 3);
    const int h   = id >> 7;
    const int rem = id & 127;
    const int mb  = (rem >> 1) * 256;          // 64 row-blocks
    const int nb  = (rem & 1) * 256;           // 2 col-blocks

    const int t    = threadIdx.x;              // 0..511
    const int lane = t & 63;
    const int w    = t >> 6;                   // 0..7
    const int wrow = (w >> 2) * 128;           // 0,128
    const int wcol = (w & 3) * 64;             // 0,64,128,192
    const int quad = lane >> 4;
    const int l16  = lane & 15;

    // staging: thread t covers row (t>>3)+q*64, chunk slot t&7; global k-chunk
    // c = (slot - (row>>1)) & 7 (R4-verified). LDS index = q*4096 + t*8.
    const int c = ((t & 7) - ((t >> 4) & 7)) & 7;
    const _Float16* Ap = A + (size_t)(mb + (t >> 3)) * Ee + c * 8;
    const _Float16* Bp = Bm + (size_t)h * Ee * Ee + (size_t)(nb + (t >> 3)) * Ee + c * 8;

#define STG_A(b, q, tt) async_ld16(&As[b][(q) * 4096 + t * 8], Ap + (tt) * 64 + (q) * 64 * Ee)
#define STG_B(b, q, tt) async_ld16(&Bs[b][(q) * 4096 + t * 8], Bp + (tt) * 64 + (q) * 64 * Ee)
#define BAR() do { asm volatile("" ::: "memory"); __builtin_amdgcn_s_barrier(); \
                   asm volatile("" ::: "memory"); } while (0)

    f32x4 acc[8][4] = {};
    f16x8 a8[4], b8[2][4];

    auto rdA = [&](int bsel, int mt, int kk) {
        int row = wrow + mt * 16 + l16;
        int sl  = ((kk * 4 + quad) + ((row >> 1) & 7)) & 7;
        return *(const f16x8*)(&As[bsel][row * 64 + sl * 8]);
    };
    auto rdB = [&](int bsel, int nt, int kk) {
        int row = wcol + nt * 16 + l16;
        int sl  = ((kk * 4 + quad) + ((row >> 1) & 7)) & 7;
        return *(const f16x8*)(&Bs[bsel][row * 64 + sl * 8]);
    };
    auto mm = [&](int mh, int kk) {
        __builtin_amdgcn_s_setprio(1);
#pragma unroll
        for (int j = 0; j < 4; ++j)
#pragma unroll
            for (int nt = 0; nt < 4; ++nt)
                acc[mh * 4 + j][nt] = __builtin_amdgcn_mfma_f32_16x16x32_f16(
                    a8[j], b8[kk][nt], acc[mh * 4 + j][nt], 0, 0, 0);
        __builtin_amdgcn_s_setprio(0);
    };

    // prologue: tile0 full (8 loads) + tile1 partial A q0,q2 + B q0-3 (6 loads)
#pragma unroll
    for (int q = 0; q < 4; ++q) { STG_A(0, q, 0); STG_B(0, q, 0); }
    STG_A(1, 0, 1); STG_A(1, 2, 1);
    STG_B(1, 0, 1); STG_B(1, 1, 1); STG_B(1, 2, 1); STG_B(1, 3, 1);
    asm volatile("s_waitcnt vmcnt(6)" ::: "memory");   // retire tile0's 8
    BAR();

#pragma unroll 1
    for (int i = 0; i < 4; ++i) {
        const int T1 = 2 * i + 1;
        const int T2 = 2 * i + 2;              // next even tile -> buf0
        const int T3 = 2 * i + 3;              // next odd tile  -> buf1
        const bool st = (i < 3);

        // ph0: buf0 kk0 mt0-3 (A q0,q2) + B kk0; stage T1 A q1,q3 -> buf1
#pragma unroll
        for (int nt = 0; nt < 4; ++nt) b8[0][nt] = rdB(0, nt, 0);
#pragma unroll
        for (int j = 0; j < 4; ++j) a8[j] = rdA(0, j, 0);
        STG_A(1, 1, T1); STG_A(1, 3, T1);
        BAR();
        mm(0, 0);
        BAR();

        // ph1: buf0 kk1 mt0-3 + B kk1
#pragma unroll
        for (int nt = 0; nt < 4; ++nt) b8[1][nt] = rdB(0, nt, 1);
#pragma unroll
        for (int j = 0; j < 4; ++j) a8[j] = rdA(0, j, 1);
        BAR();
        mm(0, 1);
        BAR();

        // ph2: buf0 kk0 mt4-7 (A q1,q3; B from regs); stage T2 A q0,q2 + B q0,q1
#pragma unroll
        for (int j = 0; j < 4; ++j) a8[j] = rdA(0, 4 + j, 0);
        if (st) { STG_A(0, 0, T2); STG_A(0, 2, T2); STG_B(0, 0, T2); STG_B(0, 1, T2); }
        BAR();
        mm(1, 0);
        BAR();

        // ph3: buf0 kk1 mt4-7; stage T2 B q2,q3; K-tile boundary wait
#pragma unroll
        for (int j = 0; j < 4; ++j) a8[j] = rdA(0, 4 + j, 1);
        if (st) { STG_B(0, 2, T2); STG_B(0, 3, T2); }
        BAR();
        mm(1, 1);
        if (st) asm volatile("s_waitcnt vmcnt(6)" ::: "memory");  // retire T1's 8
        else    asm volatile("s_waitcnt vmcnt(0)" ::: "memory");  // last tile
        BAR();

        // ph4: buf1 kk0 mt0-3 + B kk0; stage T2 A q1,q3 -> buf0
#pragma unroll
        for (int nt = 0; nt < 4; ++nt) b8[0][nt] = rdB(1, nt, 0);
#pragma unroll
        for (int j = 0; j < 4; ++j) a8[j] = rdA(1, j, 0);
        if (st) { STG_A(0, 1, T2); STG_A(0, 3, T2); }
        BAR();
        mm(0, 0);
        BAR();

        // ph5: buf1 kk1 mt0-3 + B kk1
#pragma unroll
        for (int nt = 0; nt < 4; ++nt) b8[1][nt] = rdB(1, nt, 1);
#pragma unroll
        for (int j = 0; j < 4; ++j) a8[j] = rdA(1, j, 1);
        BAR();
        mm(0, 1);
        BAR();

        // ph6: buf1 kk0 mt4-7; stage T3 A q0,q2 + B q0,q1 -> buf1
#pragma unroll
        for (int j = 0; j < 4; ++j) a8[j] = rdA(1, 4 + j, 0);
        if (st) { STG_A(1, 0, T3); STG_A(1, 2, T3); STG_B(1, 0, T3); STG_B(1, 1, T3); }
        BAR();
        mm(1, 0);
        BAR();

        // ph7: buf1 kk1 mt4-7; stage T3 B q2,q3; K-tile boundary wait
#pragma unroll
        for (int j = 0; j < 4; ++j) a8[j] = rdA(1, 4 + j, 1);
        if (st) { STG_B(1, 2, T3); STG_B(1, 3, T3); }
        BAR();
        mm(1, 1);
        if (st) {
            asm volatile("s_waitcnt vmcnt(6)" ::: "memory");      // retire T2's 8
            BAR();
        }
    }
#undef STG_A
#undef STG_B
#undef BAR

    // BN partial sums: reduce over rows (mt,r) then across quads (lanes xor 16,32)
#pragma unroll
    for (int nt = 0; nt < 4; ++nt) {
        float sv = 0.f, ss = 0.f;
#pragma unroll
        for (int mt = 0; mt < 8; ++mt)
#pragma unroll
            for (int rr = 0; rr < 4; ++rr) { float v = acc[mt][nt][rr]; sv += v; ss += v * v; }
        sv += __shfl_xor(sv, 16, 64); sv += __shfl_xor(sv, 32, 64);
        ss += __shfl_xor(ss, 16, 64); ss += __shfl_xor(ss, 32, 64);
        if (quad == 0) {
            int col = nb + wcol + nt * 16 + l16;
            atomicAdd(&sums[h * Ee + col], sv);
            atomicAdd(&sumsq[h * Ee + col], ss);
        }
    }

    // store C (f16): C/D layout col=lane&15, row=quad*4+reg
    _Float16* Cp = C + (size_t)h * Nn * Ee;
#pragma unroll
    for (int mt = 0; mt < 8; ++mt)
#pragma unroll
        for (int rr = 0; rr < 4; ++rr) {
            int row = mb + wrow + mt * 16 + quad * 4 + rr;
            size_t off = (size_t)row * Ee + nb + wcol + l16;
#pragma unroll
            for (int nt = 0; nt < 4; ++nt)
                Cp[off + nt * 16] = (_Float16)acc[mt][nt][rr];
        }
}

// ---------------- K2: finalize BN stats into affine coefs -----------------------
__global__ __launch_bounds__(256) void stats_kernel(const float* __restrict__ sums,
                                                    const float* __restrict__ sumsq,
                                                    const float* __restrict__ bnw,
                                                    const float* __restrict__ bnb,
                                                    float* __restrict__ cA,
                                                    float* __restrict__ cB) {
    int i = blockIdx.x * 256 + threadIdx.x;    // 0..4095
    float mean = sums[i] * (1.0f / Nn);
    float var  = sumsq[i] * (1.0f / Nn) - mean * mean;
    float inv  = rsqrtf(var + BN_EPS_);
    float a    = bnw[i] * inv;
    cA[i] = a;
    cB[i] = bnb[i] - mean * a;
}

// ---------------- K3: per-row head scan: sparsemax (Michelot, max-seeded) -------
// Measured 98.7 us via R11 double-launch -- at/below the pure-HBM traffic
// floor estimate (L3 absorbs part of lg). Internal restructurings (max-seed,
// 2-rows-per-wave) null -> bandwidth-bound, at roofline.
__global__ __launch_bounds__(256) void rows_kernel(const float* __restrict__ x,
                                                   const _Float16* __restrict__ lg,
                                                   const float* __restrict__ cA,
                                                   const float* __restrict__ cB,
                                                   float* __restrict__ out) {
    const int n    = blockIdx.x * 4 + (threadIdx.x >> 6);
    const int lane = threadIdx.x & 63;
    const int e0   = lane * 4;                 // first chunk; second at +256
    const int bb   = n >> 9;                   // n / Tt
    const int tt   = n & 511;                  // n % Tt

    float xr[8], prior[8];
    {
        const float* xp = x + (size_t)n * Ee;
        float4 x0 = *(const float4*)(xp + e0);
        float4 x1 = *(const float4*)(xp + 256 + e0);
        xr[0]=x0.x; xr[1]=x0.y; xr[2]=x0.z; xr[3]=x0.w;
        xr[4]=x1.x; xr[5]=x1.y; xr[6]=x1.z; xr[7]=x1.w;
    }
#pragma unroll
    for (int j = 0; j < 8; ++j) prior[j] = 1.0f;

    float* omx = out;                               // (H,B,T,E) flat = (H,N,E)
    float* omk = out + (size_t)Hh * Nn * Ee;        // (B,H,T,E)

    const _Float16* lrow = lg + (size_t)n * Ee;
    f16x4 l0 = *(const f16x4*)(lrow + e0);
    f16x4 l1 = *(const f16x4*)(lrow + 256 + e0);

#pragma unroll 1
    for (int h = 0; h < Hh; ++h) {
        // depth-1 prefetch of next head's logits (independent of prior chain)
        f16x4 p0 = l0, p1 = l1;
        if (h + 1 < Hh) {
            const _Float16* lnx = lrow + (size_t)(h + 1) * Nn * Ee;
            p0 = *(const f16x4*)(lnx + e0);
            p1 = *(const f16x4*)(lnx + 256 + e0);
        }
        float z[8];
        {
            const float* ap = cA + h * Ee + e0;
            const float* bp = cB + h * Ee + e0;
            float4 a0 = *(const float4*)(ap);
            float4 b0 = *(const float4*)(bp);
            float4 a1 = *(const float4*)(ap + 256);
            float4 b1 = *(const float4*)(bp + 256);
            z[0] = ((float)l0[0] * a0.x + b0.x) * prior[0];
            z[1] = ((float)l0[1] * a0.y + b0.y) * prior[1];
            z[2] = ((float)l0[2] * a0.z + b0.z) * prior[2];
            z[3] = ((float)l0[3] * a0.w + b0.w) * prior[3];
            z[4] = ((float)l1[0] * a1.x + b1.x) * prior[4];
            z[5] = ((float)l1[1] * a1.y + b1.y) * prior[5];
            z[6] = ((float)l1[2] * a1.z + b1.z) * prior[6];
            z[7] = ((float)l1[3] * a1.w + b1.w) * prior[7];
        }

        // Michelot seeded at tau0 = max - 1 (exact sparsemax threshold).
        float mx = z[0];
#pragma unroll
        for (int j = 1; j < 8; ++j) mx = fmaxf(mx, z[j]);
        float tau = dpp_max64(mx) - 1.0f;
        int cprev = -1;
#pragma unroll 1
        for (int it = 0; it < 64; ++it) {
            float s2 = 0.f;
            int cnt = 0;
#pragma unroll
            for (int j = 0; j < 8; ++j) {
                bool p = z[j] > tau;
                s2 += p ? z[j] : 0.0f;
                cnt += (int)__popcll(__ballot(p));
            }
            float S = dpp_sum64(s2);
            if (cnt == cprev) break;
            cprev = cnt;
            tau = (S - 1.0f) / (float)cnt;
        }

        size_t oxoff = ((size_t)h * Nn + n) * Ee + e0;
        size_t okoff = (((size_t)bb * Hh + h) * Tt + tt) * Ee + e0;
        f32x4 vx, vm;
#pragma unroll
        for (int j = 0; j < 4; ++j) {
            float m = fmaxf(z[j] - tau, 0.0f);
            prior[j] *= fmaxf(GAMMA_ - m, 0.0f);
            vm[j] = m; vx[j] = xr[j] * m;
        }
        __builtin_nontemporal_store(vx, (f32x4*)(omx + oxoff));
        __builtin_nontemporal_store(vm, (f32x4*)(omk + okoff));
#pragma unroll
        for (int j = 0; j < 4; ++j) {
            float m = fmaxf(z[4 + j] - tau, 0.0f);
            prior[4 + j] *= fmaxf(GAMMA_ - m, 0.0f);
            vm[j] = m; vx[j] = xr[4 + j] * m;
        }
        __builtin_nontemporal_store(vx, (f32x4*)(omx + oxoff + 256));
        __builtin_nontemporal_store(vm, (f32x4*)(omk + okoff + 256));
        l0 = p0; l1 = p1;
    }
}

extern "C" void kernel_launch(void* const* d_in, const int* in_sizes, int n_in,
                              void* d_out, int out_size, void* d_ws, size_t ws_size,
                              hipStream_t stream) {
    const float* x   = (const float*)d_in[0];
    const float* W   = (const float*)d_in[1];
    const float* bnw = (const float*)d_in[2];
    const float* bnb = (const float*)d_in[3];
    float* out = (float*)d_out;

    uint8_t* ws = (uint8_t*)d_ws;
    _Float16* xh = (_Float16*)(ws);                    // 16,777,216 B
    _Float16* wh = (_Float16*)(ws + 16777216);         //  4,194,304 B
    _Float16* lg = (_Float16*)(ws + 20971520);         // 134,217,728 B
    float* sums  = (float*)(ws + 155189248);           // 16,384 B
    float* sumsq = (float*)(ws + 155205632);           // 16,384 B
    float* cA    = (float*)(ws + 155222016);           // 16,384 B
    float* cB    = (float*)(ws + 155238400);           // 16,384 B (total ~148 MB)

    cvt_kernel<<<10240, 256, 0, stream>>>(x, W, xh, wh, sums);   // also zeros sums+sumsq
    gemm_kernel<<<1024, 512, 0, stream>>>(xh, wh, lg, sums, sumsq);
    stats_kernel<<<16, 256, 0, stream>>>(sums, sumsq, bnw, bnb, cA, cB);
    rows_kernel<<<4096, 256, 0, stream>>>(x, lg, cA, cB, out);
}